// Round 4
// baseline (12864.497 us; speedup 1.0000x reference)
//
#include <hip/hip_runtime.h>
#include <hip/hip_bf16.h>

// Problem constants
#define T_ 512
#define B_ 64
#define I_ 256
#define H_ 512
#define O_ 256
#define NQB 80              // 8 XCD lanes x 10 roles; domains on XCD lanes 0..3
#define NTHR 512
#define NTOT (NQB * NTHR)

typedef unsigned short u16;
typedef unsigned int u32;
typedef unsigned long long u64;
typedef short bf16x8 __attribute__((ext_vector_type(8)));   // 16 B = 4 VGPRs
typedef float f32x4 __attribute__((ext_vector_type(4)));
typedef u32 u32x4 __attribute__((ext_vector_type(4)));

// ---- control block (bytes 0..4095 of ws, zeroed by init_cnt) ----
#define CT_LIN   0         // u32 linf[8]  (slow copy): linear (mt,q) consumed h2{linf}
#define CT_LINF  32        // u32 linff[8] (fast copy, sc0)
#define CT_B0    64        // one-time init barrier counter

// ---- workspace layout (bytes) ----
#define WS_XBF   4096
#define WS_WHH1  (WS_XBF   + 16777216)
#define WS_WIH1  (WS_WHH1  + 2097152)
#define WS_WIH2  (WS_WIH1  + 1048576)
#define WS_WHH2  (WS_WIH2  + 2097152)
#define WS_WLIN  (WS_WHH2  + 2097152)
#define WS_B1    (WS_WLIN  + 262144)
#define WS_B2    (WS_B1    + 8192)
// tagged h rings: word = (tag<<16) | bf16(h). tile = (slot,mt): 16 rows x 512 u32
// SLOW rings: agent-scope (LLC) protocol — proven (round 1).
#define WS_H1T   (WS_B2    + 8192)      // 2 slots x 4 domains x 8192 u32 = 262144 B
#define WS_H2T   (WS_H1T   + 262144)    // 4 slots x 4 domains x 8192 u32 = 524288 B
// FAST rings: identical layout, sc0 stores/loads (XCD-L2 coherence point).
#define WS_H1F   (WS_H2T   + 524288)    // 262144 B
#define WS_H2F   (WS_H1F   + 262144)    // 524288 B
#define WS_END   (WS_H2F   + 524288)

__device__ __forceinline__ u16 f2bf(float f) {
  union { float f; unsigned u; } v; v.f = f;
  unsigned r = v.u + 0x7FFFu + ((v.u >> 16) & 1u);
  return (u16)(r >> 16);
}
__device__ __forceinline__ float sigm(float x)  { return 1.0f / (1.0f + __expf(-x)); }
__device__ __forceinline__ float tanh_(float x) { return 1.0f - 2.0f / (__expf(2.0f * x) + 1.0f); }
__device__ __forceinline__ bf16x8 ldg8(const u16* p) { return *(const bf16x8*)p; }
__device__ __forceinline__ u64 ald64(const u64* p) {
  return __hip_atomic_load((u64*)p, __ATOMIC_RELAXED, __HIP_MEMORY_SCOPE_AGENT);
}
__device__ __forceinline__ void ast32(u32* p, u32 v) {
  __hip_atomic_store(p, v, __ATOMIC_RELAXED, __HIP_MEMORY_SCOPE_AGENT);
}
// dual ring-word store: sc0 store -> fast ring (this XCD's L2, write-through L1);
// agent store -> slow ring (LLC, proven round-1 protocol). Both fire-and-forget.
__device__ __forceinline__ void stw2(u32* fp, u32* sp, u32 v) {
  asm volatile("global_store_dword %0, %1, off sc0" :: "v"(fp), "v"(v) : "memory");
  ast32(sp, v);
}
#define MFMA16(a, b, c) __builtin_amdgcn_mfma_f32_16x16x32_bf16((a), (b), (c), 0, 0, 0)

__device__ __forceinline__ void cvt8(const float* s, u16* dst) {
  bf16x8 v;
  #pragma unroll
  for (int jj = 0; jj < 8; jj++) v[jj] = (short)f2bf(s[jj]);
  *(bf16x8*)dst = v;
}

// Poll one 2-row slice (16 u32/lane = 64B) of a tagged tile until every word's
// tag==tag; payloads (already in regs) are packed into pk[8].
// Phase 1 (if fastok): sc0 loads on the FAST ring — L1-bypass, served by this
// XCD's L2. Bounded: after 4096 failed iterations, fastok goes false forever
// (sticky) and we drop to phase 2. Phase 2: agent loads on the SLOW ring —
// byte-identical to the round-1 proven protocol. Hang-proof by construction.
template<bool LINCHK, int SLP>
__device__ __forceinline__ void pollT(const u32* fb, const u64* sb, u32 tag,
                                      const u32* lff, const u32* lfs, int ltgt,
                                      u32* pk, bool& fastok) {
  if (fastok) {
    int it = 0;
    while (1) {
      u32 w[16];
      bool ok = true;
      u32x4 A, B2, C2, D2;
      asm volatile(
        "global_load_dwordx4 %0, %4, off sc0\n\t"
        "global_load_dwordx4 %1, %4, off offset:16 sc0\n\t"
        "global_load_dwordx4 %2, %4, off offset:32 sc0\n\t"
        "global_load_dwordx4 %3, %4, off offset:48 sc0\n\t"
        "s_waitcnt vmcnt(0)"
        : "=&v"(A), "=&v"(B2), "=&v"(C2), "=&v"(D2)
        : "v"(fb)
        : "memory");
      #pragma unroll
      for (int m = 0; m < 4; m++) {
        w[m] = A[m]; w[4 + m] = B2[m]; w[8 + m] = C2[m]; w[12 + m] = D2[m];
      }
      if (LINCHK) {
        u32 lv;
        asm volatile("global_load_dword %0, %1, off sc0\n\ts_waitcnt vmcnt(0)"
                     : "=&v"(lv) : "v"(lff) : "memory");
        ok = (int)lv >= ltgt;
      }
      #pragma unroll
      for (int m = 0; m < 16; m++) ok = ok && ((w[m] >> 16) == tag);
      if (__all(ok)) {
        #pragma unroll
        for (int m = 0; m < 8; m++)
          pk[m] = (w[2 * m] & 0xFFFFu) | (w[2 * m + 1] << 16);
        return;
      }
      if (++it >= 4096) { fastok = false; break; }   // sticky fallback
    }
  }
  while (1) {
    u64 pv[8];
    #pragma unroll
    for (int m = 0; m < 8; m++) pv[m] = ald64(sb + m);
    bool ok = true;
    #pragma unroll
    for (int m = 0; m < 8; m++)
      ok = ok && (((u32)(pv[m] >> 16) & 0xFFFFu) == tag)
              && ((u32)(pv[m] >> 48) == tag);
    if (LINCHK)
      ok = ok && ((int)__hip_atomic_load(lfs, __ATOMIC_RELAXED,
                                         __HIP_MEMORY_SCOPE_AGENT) >= ltgt);
    if (__all(ok)) {
      #pragma unroll
      for (int m = 0; m < 8; m++)
        pk[m] = (u32)(pv[m] & 0xFFFFu) | (((u32)(pv[m] >> 32) & 0xFFFFu) << 16);
      return;
    }
    if (SLP) __builtin_amdgcn_s_sleep(SLP);
  }
}

// One-time init barrier. threadfence = device release+acquire: wbl2 flushes the
// plain-written pack/init data; inv drops stale L1/L2 lines from prior dispatch.
__device__ __forceinline__ void gbar0(u32* cnt, unsigned target) {
  __syncthreads();
  if (threadIdx.x == 0) {
    __threadfence();
    __hip_atomic_fetch_add(cnt, 1u, __ATOMIC_RELAXED, __HIP_MEMORY_SCOPE_AGENT);
    while (__hip_atomic_load(cnt, __ATOMIC_RELAXED, __HIP_MEMORY_SCOPE_AGENT) < target)
      __builtin_amdgcn_s_sleep(2);
    __threadfence();
  }
  __syncthreads();
}

__global__ void init_cnt(char* ws) {
  for (int i = threadIdx.x; i < 1024; i += 256)
    __hip_atomic_store((u32*)ws + i, 0u, __ATOMIC_RELAXED, __HIP_MEMORY_SCOPE_AGENT);
}

__global__ void __launch_bounds__(NTHR, 1) lstm_ae_kernel(
    const float* __restrict__ xin,
    const float* __restrict__ Wih1, const float* __restrict__ Whh1,
    const float* __restrict__ bih1, const float* __restrict__ bhh1,
    const float* __restrict__ Wih2, const float* __restrict__ Whh2,
    const float* __restrict__ bih2, const float* __restrict__ bhh2,
    const float* __restrict__ Wlin, const float* __restrict__ blin,
    const float* __restrict__ h10, const float* __restrict__ c10,
    const float* __restrict__ h20, const float* __restrict__ c20,
    float* __restrict__ out, char* __restrict__ ws) {
  char* ctrl = ws;
  u32* linf  = (u32*)(ctrl + CT_LIN);
  u32* linff = (u32*)(ctrl + CT_LINF);
  u16* xbf   = (u16*)(ws + WS_XBF);
  u16* whh1f = (u16*)(ws + WS_WHH1);
  u16* wih1f = (u16*)(ws + WS_WIH1);
  u16* wih2f = (u16*)(ws + WS_WIH2);
  u16* whh2f = (u16*)(ws + WS_WHH2);
  u16* wlinf = (u16*)(ws + WS_WLIN);
  float* b1  = (float*)(ws + WS_B1);
  float* b2  = (float*)(ws + WS_B2);
  u32* h1s   = (u32*)(ws + WS_H1T);
  u32* h2s   = (u32*)(ws + WS_H2T);
  u32* h1fb  = (u32*)(ws + WS_H1F);
  u32* h2fb  = (u32*)(ws + WS_H2F);
  const u64* h1u = (const u64*)(ws + WS_H1T);
  const u64* h2u = (const u64*)(ws + WS_H2T);

  __shared__ __align__(16) u16 Ald[16 * 512];   // staged h tile (bf16, swizzled)
  __shared__ float exch[4 * 16 * 68];           // gate preact exchange

  const int x    = blockIdx.x & 7;              // XCD lane (round-robin dispatch)
  const int slot = blockIdx.x >> 3;             // role 0..9
  const int tid  = blockIdx.x * NTHR + threadIdx.x;

  // ---------------- phase 0: convert/pack (proven layouts) ----------------
  for (int c = tid; c < T_ * B_ * I_ / 8; c += NTOT)
    cvt8(xin + c * 8, xbf + c * 8);
  for (int c = tid; c < (1 << 17); c += NTOT) {
    int lane = c & 63, kt = (c >> 6) & 15, g = (c >> 10) & 3, n = c >> 12;
    int row = g * 512 + n * 16 + (lane & 15);
    int k   = kt * 32 + (lane >> 4) * 8;
    cvt8(Whh1 + row * 512 + k, whh1f + c * 8);
  }
  for (int c = tid; c < (1 << 16); c += NTOT) {
    int lane = c & 63, kt = (c >> 6) & 7, g = (c >> 9) & 3, n = c >> 11;
    int row = g * 512 + n * 16 + (lane & 15);
    int k   = kt * 32 + (lane >> 4) * 8;
    cvt8(Wih1 + row * 256 + k, wih1f + c * 8);
  }
  for (int c = tid; c < (1 << 17); c += NTOT) {
    int lane = c & 63, kt = (c >> 6) & 15, g = (c >> 10) & 3, n = c >> 12;
    int row = g * 512 + n * 16 + (lane & 15);
    int k   = kt * 32 + (lane >> 4) * 8;
    cvt8(Wih2 + row * 512 + k, wih2f + c * 8);
    cvt8(Whh2 + row * 512 + k, whh2f + c * 8);
  }
  for (int c = tid; c < (1 << 14); c += NTOT) {
    int lane = c & 63, kt = (c >> 6) & 15, nt = (c >> 10) & 1, l = c >> 11;
    int row = l * 32 + nt * 16 + (lane & 15);
    int k   = kt * 32 + (lane >> 4) * 8;
    cvt8(Wlin + row * 512 + k, wlinf + c * 8);
  }
  for (int i2 = tid; i2 < 2048; i2 += NTOT) {
    b1[i2] = bih1[i2] + bhh1[i2];
    b2[i2] = bih2[i2] + bhh2[i2];
  }
  // tagged ring init (BOTH rings): slot0 <- initial h (tag 0); rest 0xFFFF
  for (int c = tid; c < (1 << 16); c += NTOT) {       // h1: 2 slots
    int s2 = c >> 15, rem = c & 32767;
    int mtd = rem >> 13, r2 = rem & 8191, row = r2 >> 9, col = r2 & 511;
    u32 v = 0xFFFF0000u;
    if (s2 == 0) v = (u32)f2bf(h10[(mtd * 16 + row) * 512 + col]);
    h1s[c] = v; h1fb[c] = v;
  }
  for (int c = tid; c < (1 << 17); c += NTOT) {       // h2: 4 slots
    int s2 = c >> 15, rem = c & 32767;
    int mtd = rem >> 13, r2 = rem & 8191, row = r2 >> 9, col = r2 & 511;
    u32 v = 0xFFFF0000u;
    if (s2 == 0) v = (u32)f2bf(h20[(mtd * 16 + row) * 512 + col]);
    h2s[c] = v; h2fb[c] = v;
  }

  gbar0((u32*)(ctrl + CT_B0), NQB);   // B0: packed data + ring init visible

  if (x >= 4) return;                 // helper lanes done
  const int mt = x;

  const int lane = threadIdx.x & 63;
  const int w    = threadIdx.x >> 6;         // wave 0..7
  const int l15  = lane & 15;
  const int l31  = lane & 31;
  const int qd   = lane >> 4;
  const int prow = 2 * w + (lane >> 5);      // poll/stage row of the 16-row tile
  const int swz  = (prow & 7) << 4;          // LDS XOR swizzle for stage writes
  const int pb32 = prow * 512 + l31 * 16;    // u32 index within a (slot,mt) tile
  const int pb64 = prow * 256 + l31 * 8;     // u64 index (slow ring)
  bool fastok = true;                        // sticky per-thread protocol choice

  // A-frag read: row=l15, K-chunk kt, sub-chunk qd (swizzle-consistent)
  #define AFRAG(ktv) (*(const bf16x8*)((const char*)Ald + l15 * 1024 + \
                       (((ktv) * 64 + qd * 16) ^ ((l15 & 7) << 4))))
  #define STAGEA(pk) do { \
      u32x4 v0_ = {(pk)[0], (pk)[1], (pk)[2], (pk)[3]}; \
      u32x4 v1_ = {(pk)[4], (pk)[5], (pk)[6], (pk)[7]}; \
      char* ab_ = (char*)Ald + prow * 1024; \
      *(u32x4*)(ab_ + ((l31 * 32 +  0) ^ swz)) = v0_; \
      *(u32x4*)(ab_ + ((l31 * 32 + 16) ^ swz)) = v1_; \
    } while (0)

  if (slot < 8) {
    // ============== gate blocks: domain mt, 64 h-cols per block ==============
    const int j  = slot;
    const int g  = w >> 1;                   // gate (i,f,g,o)
    const int half = w & 1;
    const int nt0 = j * 4 + half * 2;        // global 16-col tiles nt0, nt0+1

    bf16x8 Wr0[16], Wr1[16];                 // recurrent weights, register-resident
    #pragma unroll
    for (int kt = 0; kt < 16; kt++) {
      Wr0[kt] = ldg8(whh1f + ((size_t)((nt0 + 0) * 4 + g) * 16 + kt) * 512 + lane * 8);
      Wr1[kt] = ldg8(whh1f + ((size_t)((nt0 + 1) * 4 + g) * 16 + kt) * 512 + lane * 8);
    }
    const float bg0 = b1[g * 512 + (nt0 + 0) * 16 + l15];
    const float bg1 = b1[g * 512 + (nt0 + 1) * 16 + l15];

    const int hcol = j * 64 + lane;          // elementwise: rows 2w,2w+1 col=lane
    float c0v = c10[(mt * 16 + 2 * w + 0) * 512 + hcol];
    float c1v = c10[(mt * 16 + 2 * w + 1) * 512 + hcol];

    const u16* wx0 = wih1f + ((size_t)((nt0 + 0) * 4 + g) * 8) * 512 + lane * 8;
    const u16* wx1 = wih1f + ((size_t)((nt0 + 1) * 4 + g) * 8) * 512 + lane * 8;
    const int axoff = (mt * 16 + l15) * 256 + qd * 8;
    const int sobase = (2 * w) * 512 + j * 64 + lane;

    f32x4 p0, p1;                            // x-projection (+bias) for step t
    {
      p0 = f32x4{bg0, bg0, bg0, bg0};
      p1 = f32x4{bg1, bg1, bg1, bg1};
      const u16* xr = xbf + axoff;
      #pragma unroll
      for (int kt = 0; kt < 8; kt++) {
        bf16x8 ax = ldg8(xr + kt * 32);
        p0 = MFMA16(ax, ldg8(wx0 + kt * 512), p0);
        p1 = MFMA16(ax, ldg8(wx1 + kt * 512), p1);
      }
    }

    // -------- encoder --------
    for (int t = 0; t < T_; t++) {
      u32 pk[8];
      pollT<false, 0>(h1fb + (size_t)((t & 1) * 4 + mt) * 8192 + pb32,
                      h1u  + (size_t)((t & 1) * 4 + mt) * 4096 + pb64,
                      (u32)t, linff, linf, 0, pk, fastok);
      STAGEA(pk);
      __syncthreads();
      f32x4 a0 = p0, a1 = p1;
      f32x4 a2 = {0.f, 0.f, 0.f, 0.f}, a3 = {0.f, 0.f, 0.f, 0.f};
      #pragma unroll
      for (int kt = 0; kt < 16; kt += 2) {
        bf16x8 af0 = AFRAG(kt), af1 = AFRAG(kt + 1);
        a0 = MFMA16(af0, Wr0[kt], a0);
        a1 = MFMA16(af0, Wr1[kt], a1);
        a2 = MFMA16(af1, Wr0[kt + 1], a2);
        a3 = MFMA16(af1, Wr1[kt + 1], a3);
      }
      a0 += a2; a1 += a3;
      #pragma unroll
      for (int r = 0; r < 4; r++) {
        exch[g * 1088 + (qd * 4 + r) * 68 + half * 32 +  0 + l15] = a0[r];
        exch[g * 1088 + (qd * 4 + r) * 68 + half * 32 + 16 + l15] = a1[r];
      }
      __syncthreads();
      {
        const size_t tb = (size_t)(((t + 1) & 1) * 4 + mt) * 8192 + sobase;
        u32* sof = h1fb + tb;
        u32* sos = h1s  + tb;
        #pragma unroll
        for (int rr = 0; rr < 2; rr++) {
          int rw = 2 * w + rr;
          float gi = exch[0 * 1088 + rw * 68 + lane];
          float gf = exch[1 * 1088 + rw * 68 + lane];
          float gg = exch[2 * 1088 + rw * 68 + lane];
          float go = exch[3 * 1088 + rw * 68 + lane];
          float cc = rr ? c1v : c0v;
          cc = sigm(gf) * cc + sigm(gi) * tanh_(gg);
          if (rr) c1v = cc; else c0v = cc;
          float hv = sigm(go) * tanh_(cc);
          stw2(sof + rr * 512, sos + rr * 512,
               (u32)f2bf(hv) | ((u32)(t + 1) << 16));
        }
      }
      // x-projection for t+1: executes in the shadow of the next poll
      if (t + 1 < T_) {
        p0 = f32x4{bg0, bg0, bg0, bg0};
        p1 = f32x4{bg1, bg1, bg1, bg1};
        const u16* xr = xbf + (size_t)(t + 1) * (B_ * I_) + axoff;
        #pragma unroll
        for (int kt = 0; kt < 8; kt++) {
          bf16x8 ax = ldg8(xr + kt * 32);
          p0 = MFMA16(ax, ldg8(wx0 + kt * 512), p0);
          p1 = MFMA16(ax, ldg8(wx1 + kt * 512), p1);
        }
      }
    }

    // -------- transition: q = b2 + h1{T} @ Wih2^T ; swap weights to LSTM2 ----
    f32x4 q0, q1;
    {
      u32 pk[8];
      pollT<false, 0>(h1fb + (size_t)(0 * 4 + mt) * 8192 + pb32,  // T even -> slot 0
                      h1u  + (size_t)(0 * 4 + mt) * 4096 + pb64,
                      (u32)T_, linff, linf, 0, pk, fastok);
      STAGEA(pk);
      __syncthreads();
      const float b20 = b2[g * 512 + (nt0 + 0) * 16 + l15];
      const float b21 = b2[g * 512 + (nt0 + 1) * 16 + l15];
      q0 = f32x4{b20, b20, b20, b20};
      q1 = f32x4{b21, b21, b21, b21};
      #pragma unroll
      for (int kt = 0; kt < 16; kt++) {
        bf16x8 af = AFRAG(kt);
        q0 = MFMA16(af, ldg8(wih2f + ((size_t)((nt0 + 0) * 4 + g) * 16 + kt) * 512 + lane * 8), q0);
        q1 = MFMA16(af, ldg8(wih2f + ((size_t)((nt0 + 1) * 4 + g) * 16 + kt) * 512 + lane * 8), q1);
      }
      #pragma unroll
      for (int kt = 0; kt < 16; kt++) {
        Wr0[kt] = ldg8(whh2f + ((size_t)((nt0 + 0) * 4 + g) * 16 + kt) * 512 + lane * 8);
        Wr1[kt] = ldg8(whh2f + ((size_t)((nt0 + 1) * 4 + g) * 16 + kt) * 512 + lane * 8);
      }
      c0v = c20[(mt * 16 + 2 * w + 0) * 512 + hcol];
      c1v = c20[(mt * 16 + 2 * w + 1) * 512 + hcol];
      __syncthreads();   // Ald reads done before decoder's first stage
    }

    // -------- decoder --------
    for (int t = 0; t < T_; t++) {
      u32 pk[8];
      const u32* lff = linff + mt * 2 + (lane & 1);
      const u32* lfs = linf  + mt * 2 + (lane & 1);
      const int ltgt = (lane < 2) ? (t - 3) : -1;     // ring back-pressure, in-round
      pollT<true, 0>(h2fb + (size_t)((t & 3) * 4 + mt) * 8192 + pb32,
                     h2u  + (size_t)((t & 3) * 4 + mt) * 4096 + pb64,
                     (u32)t, lff, lfs, ltgt, pk, fastok);
      STAGEA(pk);
      __syncthreads();
      f32x4 a0 = q0, a1 = q1;
      f32x4 a2 = {0.f, 0.f, 0.f, 0.f}, a3 = {0.f, 0.f, 0.f, 0.f};
      #pragma unroll
      for (int kt = 0; kt < 16; kt += 2) {
        bf16x8 af0 = AFRAG(kt), af1 = AFRAG(kt + 1);
        a0 = MFMA16(af0, Wr0[kt], a0);
        a1 = MFMA16(af0, Wr1[kt], a1);
        a2 = MFMA16(af1, Wr0[kt + 1], a2);
        a3 = MFMA16(af1, Wr1[kt + 1], a3);
      }
      a0 += a2; a1 += a3;
      #pragma unroll
      for (int r = 0; r < 4; r++) {
        exch[g * 1088 + (qd * 4 + r) * 68 + half * 32 +  0 + l15] = a0[r];
        exch[g * 1088 + (qd * 4 + r) * 68 + half * 32 + 16 + l15] = a1[r];
      }
      __syncthreads();
      {
        const size_t tb = (size_t)(((t + 1) & 3) * 4 + mt) * 8192 + sobase;
        u32* sof = h2fb + tb;
        u32* sos = h2s  + tb;
        #pragma unroll
        for (int rr = 0; rr < 2; rr++) {
          int rw = 2 * w + rr;
          float gi = exch[0 * 1088 + rw * 68 + lane];
          float gf = exch[1 * 1088 + rw * 68 + lane];
          float gg = exch[2 * 1088 + rw * 68 + lane];
          float go = exch[3 * 1088 + rw * 68 + lane];
          float cc = rr ? c1v : c0v;
          cc = sigm(gf) * cc + sigm(gi) * tanh_(gg);
          if (rr) c1v = cc; else c0v = cc;
          float hv = sigm(go) * tanh_(cc);
          stw2(sof + rr * 512, sos + rr * 512,
               (u32)f2bf(hv) | ((u32)(t + 1) << 16));
        }
      }
    }
  } else {
    // ============== linear blocks: (mt, q), wave = out col-tile ==============
    const int qq = slot - 8;
    const int to = qq * 8 + w;               // out col-tile 0..15
    bf16x8 Wl[16];
    #pragma unroll
    for (int kt = 0; kt < 16; kt++)
      Wl[kt] = ldg8(wlinf + ((size_t)to * 16 + kt) * 512 + lane * 8);
    const float bl = blin[to * 16 + l15];
    u32* lfpf = linff + mt * 2 + qq;
    u32* lfps = linf  + mt * 2 + qq;

    // out[s] = W_lin . h2{s+1}
    for (int s = 0; s < T_; s++) {
      u32 pk[8];
      pollT<false, 2>(h2fb + (size_t)(((s + 1) & 3) * 4 + mt) * 8192 + pb32,
                      h2u  + (size_t)(((s + 1) & 3) * 4 + mt) * 4096 + pb64,
                      (u32)(s + 1), linff, linf, 0, pk, fastok);
      STAGEA(pk);
      __syncthreads();
      if (threadIdx.x == 0) stw2(lfpf, lfps, (u32)(s + 1));   // release ring slot
      f32x4 o = {bl, bl, bl, bl};
      #pragma unroll
      for (int kt = 0; kt < 16; kt++) {
        bf16x8 af = AFRAG(kt);
        o = MFMA16(af, Wl[kt], o);
      }
      float* op = out + ((size_t)s * 64 + mt * 16 + qd * 4) * 256 + to * 16 + l15;
      #pragma unroll
      for (int r = 0; r < 4; r++) op[(size_t)r * 256] = o[r];
      __syncthreads();                       // Ald reads done before next stage
    }
  }
  #undef AFRAG
  #undef STAGEA
}

extern "C" void kernel_launch(void* const* d_in, const int* in_sizes, int n_in,
                              void* d_out, int out_size, void* d_ws, size_t ws_size,
                              hipStream_t stream) {
  (void)in_sizes; (void)n_in; (void)out_size; (void)ws_size;
  const float* xin  = (const float*)d_in[0];
  const float* Wih1 = (const float*)d_in[1];
  const float* Whh1 = (const float*)d_in[2];
  const float* bih1 = (const float*)d_in[3];
  const float* bhh1 = (const float*)d_in[4];
  const float* Wih2 = (const float*)d_in[5];
  const float* Whh2 = (const float*)d_in[6];
  const float* bih2 = (const float*)d_in[7];
  const float* bhh2 = (const float*)d_in[8];
  const float* Wlin = (const float*)d_in[9];
  const float* blin = (const float*)d_in[10];
  const float* h10  = (const float*)d_in[11];
  const float* c10  = (const float*)d_in[12];
  const float* h20  = (const float*)d_in[13];
  const float* c20  = (const float*)d_in[14];
  float* out = (float*)d_out;
  char* ws   = (char*)d_ws;

  init_cnt<<<dim3(1), dim3(256), 0, stream>>>(ws);

  void* args[] = { (void*)&xin, (void*)&Wih1, (void*)&Whh1, (void*)&bih1, (void*)&bhh1,
                   (void*)&Wih2, (void*)&Whh2, (void*)&bih2, (void*)&bhh2,
                   (void*)&Wlin, (void*)&blin, (void*)&h10, (void*)&c10,
                   (void*)&h20, (void*)&c20, (void*)&out, (void*)&ws };
  hipLaunchCooperativeKernel((void*)lstm_ae_kernel, dim3(NQB), dim3(NTHR),
                             args, 0, stream);
}

// Round 5
// 4770.297 us; speedup vs baseline: 2.6968x; 2.6968x over previous
//
#include <hip/hip_runtime.h>
#include <hip/hip_bf16.h>

// Problem constants
#define T_ 512
#define B_ 64
#define I_ 256
#define H_ 512
#define O_ 256
#define NGB 32              // gate blocks: 4 domains x 8 blocks (64 h-cols each)
#define NLB 8               // linear blocks: 4 domains x 2 (128 out-cols each)
#define NBLK (NGB + NLB)
#define NTHR 512
#define NTOT (NBLK * NTHR)

typedef unsigned short u16;
typedef unsigned int u32;
typedef unsigned long long u64;
typedef short bf16x8 __attribute__((ext_vector_type(8)));   // 16 B = 4 VGPRs
typedef float f32x4 __attribute__((ext_vector_type(4)));
typedef u32 u32x4 __attribute__((ext_vector_type(4)));

// ---- control block (bytes 0..4095 of ws, zeroed by init_cnt) ----
#define CT_LIN   0         // u32 linf[8]: linear block (mt,q) consumed h2{linf}
#define CT_B0    64        // one-time init barrier counter

// ---- workspace layout (bytes) ----
#define WS_XBF   4096
#define WS_WHH1  (WS_XBF   + 16777216)
#define WS_WIH1  (WS_WHH1  + 2097152)
#define WS_WIH2  (WS_WIH1  + 1048576)
#define WS_WHH2  (WS_WIH2  + 2097152)
#define WS_WLIN  (WS_WHH2  + 2097152)
#define WS_B1    (WS_WLIN  + 262144)
#define WS_B2    (WS_B1    + 8192)
// tagged h rings: word = (tag<<16) | bf16(h). tile = (slot,mt): 16 rows x 512 u32
#define WS_H1T   (WS_B2    + 8192)      // 2 slots x 4 domains x 8192 u32 = 262144 B
#define WS_H2T   (WS_H1T   + 262144)    // 4 slots x 4 domains x 8192 u32 = 524288 B
#define WS_END   (WS_H2T   + 524288)

__device__ __forceinline__ u16 f2bf(float f) {
  union { float f; unsigned u; } v; v.f = f;
  unsigned r = v.u + 0x7FFFu + ((v.u >> 16) & 1u);
  return (u16)(r >> 16);
}
__device__ __forceinline__ float sigm(float x)  { return 1.0f / (1.0f + __expf(-x)); }
__device__ __forceinline__ float tanh_(float x) { return 1.0f - 2.0f / (__expf(2.0f * x) + 1.0f); }
__device__ __forceinline__ bf16x8 ldg8(const u16* p) { return *(const bf16x8*)p; }
__device__ __forceinline__ void ast32(u32* p, u32 v) {
  __hip_atomic_store(p, v, __ATOMIC_RELAXED, __HIP_MEMORY_SCOPE_AGENT);
}
#define MFMA16(a, b, c) __builtin_amdgcn_mfma_f32_16x16x32_bf16((a), (b), (c), 0, 0, 0)

__device__ __forceinline__ void cvt8(const float* s, u16* dst) {
  bf16x8 v;
  #pragma unroll
  for (int jj = 0; jj < 8; jj++) v[jj] = (short)f2bf(s[jj]);
  *(bf16x8*)dst = v;
}

// Poll one 2-row slice (16 u32/lane = 64B) of a tagged tile until every word's
// tag==tag; payloads (already in regs) are packed into pk[8].
// KEY CHANGE vs round-1 (proven 5963us): the 8 agent atomic loads per iteration
// serialized into 8 dependent LLC round trips (~3.5K cy/iter). Batch them as
// 4x global_load_dwordx4 sc0 sc1 (L1+L2 bypass -> LLC, same coherence point as
// agent atomics) under ONE s_waitcnt -> ~1 LLC latency per iteration.
// LINCHK folds the back-pressure word into the same batch (no extra trip).
template<bool LINCHK, int SLP>
__device__ __forceinline__ void pollTile(const u32* pbw, u32 tag,
                                         const u32* lfp, int ltgt, u32* pk) {
  while (1) {
    u32 w[16];
    bool ok = true;
    u32x4 A, B2, C2, D2;
    if (LINCHK) {
      u32 lv;
      asm volatile(
        "global_load_dwordx4 %0, %5, off sc0 sc1\n\t"
        "global_load_dwordx4 %1, %5, off offset:16 sc0 sc1\n\t"
        "global_load_dwordx4 %2, %5, off offset:32 sc0 sc1\n\t"
        "global_load_dwordx4 %3, %5, off offset:48 sc0 sc1\n\t"
        "global_load_dword   %4, %6, off sc0 sc1\n\t"
        "s_waitcnt vmcnt(0)"
        : "=&v"(A), "=&v"(B2), "=&v"(C2), "=&v"(D2), "=&v"(lv)
        : "v"(pbw), "v"(lfp)
        : "memory");
      ok = (int)lv >= ltgt;
    } else {
      asm volatile(
        "global_load_dwordx4 %0, %4, off sc0 sc1\n\t"
        "global_load_dwordx4 %1, %4, off offset:16 sc0 sc1\n\t"
        "global_load_dwordx4 %2, %4, off offset:32 sc0 sc1\n\t"
        "global_load_dwordx4 %3, %4, off offset:48 sc0 sc1\n\t"
        "s_waitcnt vmcnt(0)"
        : "=&v"(A), "=&v"(B2), "=&v"(C2), "=&v"(D2)
        : "v"(pbw)
        : "memory");
    }
    #pragma unroll
    for (int m = 0; m < 4; m++) {
      w[m] = A[m]; w[4 + m] = B2[m]; w[8 + m] = C2[m]; w[12 + m] = D2[m];
    }
    #pragma unroll
    for (int m = 0; m < 16; m++) ok = ok && ((w[m] >> 16) == tag);
    if (__all(ok)) {
      #pragma unroll
      for (int m = 0; m < 8; m++)
        pk[m] = (w[2 * m] & 0xFFFFu) | (w[2 * m + 1] << 16);
      return;
    }
    if (SLP) __builtin_amdgcn_s_sleep(SLP);
  }
}

// One-time init barrier (heavy fences OK once: flushes packed weights/x to LLC).
__device__ __forceinline__ void gbar0(u32* cnt, unsigned target) {
  __syncthreads();
  if (threadIdx.x == 0) {
    __threadfence();
    __hip_atomic_fetch_add(cnt, 1u, __ATOMIC_RELAXED, __HIP_MEMORY_SCOPE_AGENT);
    while (__hip_atomic_load(cnt, __ATOMIC_RELAXED, __HIP_MEMORY_SCOPE_AGENT) < target)
      __builtin_amdgcn_s_sleep(2);
    __threadfence();
  }
  __syncthreads();
}

__global__ void init_cnt(char* ws) {
  for (int i = threadIdx.x; i < 1024; i += 256)
    __hip_atomic_store((u32*)ws + i, 0u, __ATOMIC_RELAXED, __HIP_MEMORY_SCOPE_AGENT);
}

__global__ void __launch_bounds__(NTHR, 1) lstm_ae_kernel(
    const float* __restrict__ xin,
    const float* __restrict__ Wih1, const float* __restrict__ Whh1,
    const float* __restrict__ bih1, const float* __restrict__ bhh1,
    const float* __restrict__ Wih2, const float* __restrict__ Whh2,
    const float* __restrict__ bih2, const float* __restrict__ bhh2,
    const float* __restrict__ Wlin, const float* __restrict__ blin,
    const float* __restrict__ h10, const float* __restrict__ c10,
    const float* __restrict__ h20, const float* __restrict__ c20,
    float* __restrict__ out, char* __restrict__ ws) {
  char* ctrl = ws;
  u32* linf  = (u32*)(ctrl + CT_LIN);
  u16* xbf   = (u16*)(ws + WS_XBF);
  u16* whh1f = (u16*)(ws + WS_WHH1);
  u16* wih1f = (u16*)(ws + WS_WIH1);
  u16* wih2f = (u16*)(ws + WS_WIH2);
  u16* whh2f = (u16*)(ws + WS_WHH2);
  u16* wlinf = (u16*)(ws + WS_WLIN);
  float* b1  = (float*)(ws + WS_B1);
  float* b2  = (float*)(ws + WS_B2);
  u32* h1s   = (u32*)(ws + WS_H1T);
  u32* h2s   = (u32*)(ws + WS_H2T);

  __shared__ __align__(16) u16 Ald[16 * 512];   // staged h tile (bf16, swizzled)
  __shared__ float exch[4 * 16 * 68];           // gate preact exchange

  const int tid = blockIdx.x * NTHR + threadIdx.x;

  // ---------------- phase 0: convert/pack (proven layouts) ----------------
  for (int c = tid; c < T_ * B_ * I_ / 8; c += NTOT)
    cvt8(xin + c * 8, xbf + c * 8);
  for (int c = tid; c < (1 << 17); c += NTOT) {
    int lane = c & 63, kt = (c >> 6) & 15, g = (c >> 10) & 3, n = c >> 12;
    int row = g * 512 + n * 16 + (lane & 15);
    int k   = kt * 32 + (lane >> 4) * 8;
    cvt8(Whh1 + row * 512 + k, whh1f + c * 8);
  }
  for (int c = tid; c < (1 << 16); c += NTOT) {
    int lane = c & 63, kt = (c >> 6) & 7, g = (c >> 9) & 3, n = c >> 11;
    int row = g * 512 + n * 16 + (lane & 15);
    int k   = kt * 32 + (lane >> 4) * 8;
    cvt8(Wih1 + row * 256 + k, wih1f + c * 8);
  }
  for (int c = tid; c < (1 << 17); c += NTOT) {
    int lane = c & 63, kt = (c >> 6) & 15, g = (c >> 10) & 3, n = c >> 12;
    int row = g * 512 + n * 16 + (lane & 15);
    int k   = kt * 32 + (lane >> 4) * 8;
    cvt8(Wih2 + row * 512 + k, wih2f + c * 8);
    cvt8(Whh2 + row * 512 + k, whh2f + c * 8);
  }
  for (int c = tid; c < (1 << 14); c += NTOT) {
    int lane = c & 63, kt = (c >> 6) & 15, nt = (c >> 10) & 1, l = c >> 11;
    int row = l * 32 + nt * 16 + (lane & 15);
    int k   = kt * 32 + (lane >> 4) * 8;
    cvt8(Wlin + row * 512 + k, wlinf + c * 8);
  }
  for (int i2 = tid; i2 < 2048; i2 += NTOT) {
    b1[i2] = bih1[i2] + bhh1[i2];
    b2[i2] = bih2[i2] + bhh2[i2];
  }
  // tagged rings: slot 0 <- initial h (tag 0); other slots <- 0xFFFF (never matches)
  for (int c = tid; c < (1 << 16); c += NTOT) {       // h1: 2 slots
    int slot = c >> 15, rem = c & 32767;
    int mtd = rem >> 13, r2 = rem & 8191, row = r2 >> 9, col = r2 & 511;
    u32 v = 0xFFFF0000u;
    if (slot == 0) v = (u32)f2bf(h10[(mtd * 16 + row) * 512 + col]);
    h1s[c] = v;
  }
  for (int c = tid; c < (1 << 17); c += NTOT) {       // h2: 4 slots
    int slot = c >> 15, rem = c & 32767;
    int mtd = rem >> 13, r2 = rem & 8191, row = r2 >> 9, col = r2 & 511;
    u32 v = 0xFFFF0000u;
    if (slot == 0) v = (u32)f2bf(h20[(mtd * 16 + row) * 512 + col]);
    h2s[c] = v;
  }

  gbar0((u32*)(ctrl + CT_B0), NBLK);   // B0: packed data + ring init at LLC

  const int lane = threadIdx.x & 63;
  const int w    = threadIdx.x >> 6;         // wave 0..7
  const int l15  = lane & 15;
  const int l31  = lane & 31;
  const int qd   = lane >> 4;
  const int prow = 2 * w + (lane >> 5);      // poll/stage row of the 16-row tile
  const int swz  = (prow & 7) << 4;          // LDS XOR swizzle for stage writes
  const int pb32 = prow * 512 + l31 * 16;    // u32 index within a (slot,mt) tile

  // A-frag read: row=l15, K-chunk kt, sub-chunk qd (swizzle-consistent with stage)
  #define AFRAG(ktv) (*(const bf16x8*)((const char*)Ald + l15 * 1024 + \
                       (((ktv) * 64 + qd * 16) ^ ((l15 & 7) << 4))))
  #define STAGEA(pk) do { \
      u32x4 v0_ = {(pk)[0], (pk)[1], (pk)[2], (pk)[3]}; \
      u32x4 v1_ = {(pk)[4], (pk)[5], (pk)[6], (pk)[7]}; \
      char* ab_ = (char*)Ald + prow * 1024; \
      *(u32x4*)(ab_ + ((l31 * 32 +  0) ^ swz)) = v0_; \
      *(u32x4*)(ab_ + ((l31 * 32 + 16) ^ swz)) = v1_; \
    } while (0)

  if (blockIdx.x < NGB) {
    // ============== gate blocks: domain mt, 64 h-cols per block ==============
    const int mt = blockIdx.x >> 3;
    const int j  = blockIdx.x & 7;
    const int g  = w >> 1;                   // gate (i,f,g,o)
    const int half = w & 1;
    const int nt0 = j * 4 + half * 2;        // global 16-col tiles nt0, nt0+1

    bf16x8 Wr0[16], Wr1[16];                 // recurrent weights, register-resident
    #pragma unroll
    for (int kt = 0; kt < 16; kt++) {
      Wr0[kt] = ldg8(whh1f + ((size_t)((nt0 + 0) * 4 + g) * 16 + kt) * 512 + lane * 8);
      Wr1[kt] = ldg8(whh1f + ((size_t)((nt0 + 1) * 4 + g) * 16 + kt) * 512 + lane * 8);
    }
    const float bg0 = b1[g * 512 + (nt0 + 0) * 16 + l15];
    const float bg1 = b1[g * 512 + (nt0 + 1) * 16 + l15];

    const int hcol = j * 64 + lane;          // elementwise: rows 2w,2w+1 col=lane
    float c0v = c10[(mt * 16 + 2 * w + 0) * 512 + hcol];
    float c1v = c10[(mt * 16 + 2 * w + 1) * 512 + hcol];

    const u16* wx0 = wih1f + ((size_t)((nt0 + 0) * 4 + g) * 8) * 512 + lane * 8;
    const u16* wx1 = wih1f + ((size_t)((nt0 + 1) * 4 + g) * 8) * 512 + lane * 8;
    const int axoff = (mt * 16 + l15) * 256 + qd * 8;
    const int sobase = (2 * w) * 512 + j * 64 + lane;

    f32x4 p0, p1;                            // x-projection (+bias) for step t
    {
      p0 = f32x4{bg0, bg0, bg0, bg0};
      p1 = f32x4{bg1, bg1, bg1, bg1};
      const u16* xr = xbf + axoff;
      #pragma unroll
      for (int kt = 0; kt < 8; kt++) {
        bf16x8 ax = ldg8(xr + kt * 32);
        p0 = MFMA16(ax, ldg8(wx0 + kt * 512), p0);
        p1 = MFMA16(ax, ldg8(wx1 + kt * 512), p1);
      }
    }

    // -------- encoder --------
    for (int t = 0; t < T_; t++) {
      u32 pk[8];
      pollTile<false, 0>(h1s + (size_t)((t & 1) * 4 + mt) * 8192 + pb32,
                         (u32)t, linf, 0, pk);
      STAGEA(pk);
      __syncthreads();
      f32x4 a0 = p0, a1 = p1;
      f32x4 a2 = {0.f, 0.f, 0.f, 0.f}, a3 = {0.f, 0.f, 0.f, 0.f};
      #pragma unroll
      for (int kt = 0; kt < 16; kt += 2) {
        bf16x8 af0 = AFRAG(kt), af1 = AFRAG(kt + 1);
        a0 = MFMA16(af0, Wr0[kt], a0);
        a1 = MFMA16(af0, Wr1[kt], a1);
        a2 = MFMA16(af1, Wr0[kt + 1], a2);
        a3 = MFMA16(af1, Wr1[kt + 1], a3);
      }
      a0 += a2; a1 += a3;
      #pragma unroll
      for (int r = 0; r < 4; r++) {
        exch[g * 1088 + (qd * 4 + r) * 68 + half * 32 +  0 + l15] = a0[r];
        exch[g * 1088 + (qd * 4 + r) * 68 + half * 32 + 16 + l15] = a1[r];
      }
      __syncthreads();
      {
        u32* so = h1s + (size_t)(((t + 1) & 1) * 4 + mt) * 8192 + sobase;
        #pragma unroll
        for (int rr = 0; rr < 2; rr++) {
          int rw = 2 * w + rr;
          float gi = exch[0 * 1088 + rw * 68 + lane];
          float gf = exch[1 * 1088 + rw * 68 + lane];
          float gg = exch[2 * 1088 + rw * 68 + lane];
          float go = exch[3 * 1088 + rw * 68 + lane];
          float cc = rr ? c1v : c0v;
          cc = sigm(gf) * cc + sigm(gi) * tanh_(gg);
          if (rr) c1v = cc; else c0v = cc;
          float hv = sigm(go) * tanh_(cc);
          ast32(so + rr * 512, (u32)f2bf(hv) | ((u32)(t + 1) << 16));
        }
      }
      // x-projection for t+1: executes in the shadow of the next poll
      if (t + 1 < T_) {
        p0 = f32x4{bg0, bg0, bg0, bg0};
        p1 = f32x4{bg1, bg1, bg1, bg1};
        const u16* xr = xbf + (size_t)(t + 1) * (B_ * I_) + axoff;
        #pragma unroll
        for (int kt = 0; kt < 8; kt++) {
          bf16x8 ax = ldg8(xr + kt * 32);
          p0 = MFMA16(ax, ldg8(wx0 + kt * 512), p0);
          p1 = MFMA16(ax, ldg8(wx1 + kt * 512), p1);
        }
      }
    }

    // -------- transition: q = b2 + h1{T} @ Wih2^T ; swap weights to LSTM2 ----
    f32x4 q0, q1;
    {
      u32 pk[8];
      pollTile<false, 0>(h1s + (size_t)(0 * 4 + mt) * 8192 + pb32,  // T even -> slot 0
                         (u32)T_, linf, 0, pk);
      STAGEA(pk);
      __syncthreads();
      const float b20 = b2[g * 512 + (nt0 + 0) * 16 + l15];
      const float b21 = b2[g * 512 + (nt0 + 1) * 16 + l15];
      q0 = f32x4{b20, b20, b20, b20};
      q1 = f32x4{b21, b21, b21, b21};
      #pragma unroll
      for (int kt = 0; kt < 16; kt++) {
        bf16x8 af = AFRAG(kt);
        q0 = MFMA16(af, ldg8(wih2f + ((size_t)((nt0 + 0) * 4 + g) * 16 + kt) * 512 + lane * 8), q0);
        q1 = MFMA16(af, ldg8(wih2f + ((size_t)((nt0 + 1) * 4 + g) * 16 + kt) * 512 + lane * 8), q1);
      }
      #pragma unroll
      for (int kt = 0; kt < 16; kt++) {
        Wr0[kt] = ldg8(whh2f + ((size_t)((nt0 + 0) * 4 + g) * 16 + kt) * 512 + lane * 8);
        Wr1[kt] = ldg8(whh2f + ((size_t)((nt0 + 1) * 4 + g) * 16 + kt) * 512 + lane * 8);
      }
      c0v = c20[(mt * 16 + 2 * w + 0) * 512 + hcol];
      c1v = c20[(mt * 16 + 2 * w + 1) * 512 + hcol];
      __syncthreads();   // Ald reads done before decoder's first stage
    }

    // -------- decoder --------
    for (int t = 0; t < T_; t++) {
      u32 pk[8];
      const u32* lfp = linf + mt * 2 + (lane & 1);
      const int ltgt = (lane < 2) ? (t - 3) : -1;     // ring back-pressure, in-round
      pollTile<true, 0>(h2s + (size_t)((t & 3) * 4 + mt) * 8192 + pb32,
                        (u32)t, lfp, ltgt, pk);
      STAGEA(pk);
      __syncthreads();
      f32x4 a0 = q0, a1 = q1;
      f32x4 a2 = {0.f, 0.f, 0.f, 0.f}, a3 = {0.f, 0.f, 0.f, 0.f};
      #pragma unroll
      for (int kt = 0; kt < 16; kt += 2) {
        bf16x8 af0 = AFRAG(kt), af1 = AFRAG(kt + 1);
        a0 = MFMA16(af0, Wr0[kt], a0);
        a1 = MFMA16(af0, Wr1[kt], a1);
        a2 = MFMA16(af1, Wr0[kt + 1], a2);
        a3 = MFMA16(af1, Wr1[kt + 1], a3);
      }
      a0 += a2; a1 += a3;
      #pragma unroll
      for (int r = 0; r < 4; r++) {
        exch[g * 1088 + (qd * 4 + r) * 68 + half * 32 +  0 + l15] = a0[r];
        exch[g * 1088 + (qd * 4 + r) * 68 + half * 32 + 16 + l15] = a1[r];
      }
      __syncthreads();
      {
        u32* so = h2s + (size_t)(((t + 1) & 3) * 4 + mt) * 8192 + sobase;
        #pragma unroll
        for (int rr = 0; rr < 2; rr++) {
          int rw = 2 * w + rr;
          float gi = exch[0 * 1088 + rw * 68 + lane];
          float gf = exch[1 * 1088 + rw * 68 + lane];
          float gg = exch[2 * 1088 + rw * 68 + lane];
          float go = exch[3 * 1088 + rw * 68 + lane];
          float cc = rr ? c1v : c0v;
          cc = sigm(gf) * cc + sigm(gi) * tanh_(gg);
          if (rr) c1v = cc; else c0v = cc;
          float hv = sigm(go) * tanh_(cc);
          ast32(so + rr * 512, (u32)f2bf(hv) | ((u32)(t + 1) << 16));
        }
      }
    }
  } else {
    // ============== linear blocks: (mt, q), wave = out col-tile ==============
    const int b  = blockIdx.x - NGB;
    const int mt = b >> 1, qq = b & 1;
    const int to = qq * 8 + w;               // out col-tile 0..15
    bf16x8 Wl[16];
    #pragma unroll
    for (int kt = 0; kt < 16; kt++)
      Wl[kt] = ldg8(wlinf + ((size_t)to * 16 + kt) * 512 + lane * 8);
    const float bl = blin[to * 16 + l15];
    u32* lfp = linf + mt * 2 + qq;

    // out[s] = W_lin . h2{s+1}
    for (int s = 0; s < T_; s++) {
      u32 pk[8];
      pollTile<false, 2>(h2s + (size_t)(((s + 1) & 3) * 4 + mt) * 8192 + pb32,
                         (u32)(s + 1), linf, 0, pk);
      STAGEA(pk);
      __syncthreads();
      if (threadIdx.x == 0) ast32(lfp, (u32)(s + 1));   // release ring slot
      f32x4 o = {bl, bl, bl, bl};
      #pragma unroll
      for (int kt = 0; kt < 16; kt++) {
        bf16x8 af = AFRAG(kt);
        o = MFMA16(af, Wl[kt], o);
      }
      float* op = out + ((size_t)s * 64 + mt * 16 + qd * 4) * 256 + to * 16 + l15;
      #pragma unroll
      for (int r = 0; r < 4; r++) op[(size_t)r * 256] = o[r];
      __syncthreads();                       // Ald reads done before next stage
    }
  }
  #undef AFRAG
  #undef STAGEA
}

extern "C" void kernel_launch(void* const* d_in, const int* in_sizes, int n_in,
                              void* d_out, int out_size, void* d_ws, size_t ws_size,
                              hipStream_t stream) {
  (void)in_sizes; (void)n_in; (void)out_size; (void)ws_size;
  const float* xin  = (const float*)d_in[0];
  const float* Wih1 = (const float*)d_in[1];
  const float* Whh1 = (const float*)d_in[2];
  const float* bih1 = (const float*)d_in[3];
  const float* bhh1 = (const float*)d_in[4];
  const float* Wih2 = (const float*)d_in[5];
  const float* Whh2 = (const float*)d_in[6];
  const float* bih2 = (const float*)d_in[7];
  const float* bhh2 = (const float*)d_in[8];
  const float* Wlin = (const float*)d_in[9];
  const float* blin = (const float*)d_in[10];
  const float* h10  = (const float*)d_in[11];
  const float* c10  = (const float*)d_in[12];
  const float* h20  = (const float*)d_in[13];
  const float* c20  = (const float*)d_in[14];
  float* out = (float*)d_out;
  char* ws   = (char*)d_ws;

  init_cnt<<<dim3(1), dim3(256), 0, stream>>>(ws);

  void* args[] = { (void*)&xin, (void*)&Wih1, (void*)&Whh1, (void*)&bih1, (void*)&bhh1,
                   (void*)&Wih2, (void*)&Whh2, (void*)&bih2, (void*)&bhh2,
                   (void*)&Wlin, (void*)&blin, (void*)&h10, (void*)&c10,
                   (void*)&h20, (void*)&c20, (void*)&out, (void*)&ws };
  hipLaunchCooperativeKernel((void*)lstm_ae_kernel, dim3(NBLK), dim3(NTHR),
                             args, 0, stream);
}